// Round 6
// baseline (629.261 us; speedup 1.0000x reference)
//
#include <hip/hip_runtime.h>
#include <stdint.h>

#define N_NODES 100000
#define N_EDGES 1600000
#define NFEAT 256
#define NHID 64
#define N_ELEMS (N_NODES * NHID)   // 6,400,000

// Config (R0-R5 fingerprint re-fit):
//   inputs  : f32  (R2: bf16-misread => NaN => all-zero signature)
//   output  : f32  ("bf16" in harness label is hardcoded f-string text)
//   dropout : JAX >=0.4.36 partitionable threefry, per element i:
//             (o0,o1) = threefry2x32(key=(0,42), x0=hi32(i)=0, x1=lo32(i)=i)
//             bits = o0 ^ o1 ; u = bitcast((bits>>9)|0x3F800000)-1 ; keep u<0.7
// Workspace: sums[128] + scaleshift[128] + agg[6.4M f32] = 25.601 MB.
// support[6.4M f32] staged in d_out (dead before apply overwrites it).

// ---------------------------------------------------------------------------
// GEMM: support[N x 64] = x[N x 256] @ W[256 x 64]  (f32)
// ---------------------------------------------------------------------------
__global__ __launch_bounds__(256) void gemm_kernel(const float* __restrict__ x,
                                                   const float* __restrict__ W,
                                                   float* __restrict__ support) {
    __shared__ float As[64][65];
    __shared__ float Bs[64][65];
    const int tid = threadIdx.x;
    const int row0 = blockIdx.x * 64;
    const int tx = tid & 15;
    const int ty = tid >> 4;
    const int lr = tid >> 4;
    const int lc = (tid & 15) * 4;

    float acc[4][4] = {};

    for (int k0 = 0; k0 < NFEAT; k0 += 64) {
        #pragma unroll
        for (int rr = 0; rr < 64; rr += 16) {
            int gr = row0 + lr + rr;
            float4 v = make_float4(0.f, 0.f, 0.f, 0.f);
            if (gr < N_NODES)
                v = *(const float4*)&x[(size_t)gr * NFEAT + k0 + lc];
            As[lr + rr][lc + 0] = v.x;
            As[lr + rr][lc + 1] = v.y;
            As[lr + rr][lc + 2] = v.z;
            As[lr + rr][lc + 3] = v.w;
        }
        #pragma unroll
        for (int rr = 0; rr < 64; rr += 16) {
            int gr = k0 + lr + rr;
            float4 v = *(const float4*)&W[(size_t)gr * NHID + lc];
            Bs[lr + rr][lc + 0] = v.x;
            Bs[lr + rr][lc + 1] = v.y;
            Bs[lr + rr][lc + 2] = v.z;
            Bs[lr + rr][lc + 3] = v.w;
        }
        __syncthreads();

        #pragma unroll
        for (int kk = 0; kk < 64; kk++) {
            float a[4], b[4];
            #pragma unroll
            for (int i = 0; i < 4; i++) a[i] = As[ty * 4 + i][kk];
            #pragma unroll
            for (int j = 0; j < 4; j++) b[j] = Bs[kk][tx * 4 + j];
            #pragma unroll
            for (int i = 0; i < 4; i++)
                #pragma unroll
                for (int j = 0; j < 4; j++)
                    acc[i][j] = fmaf(a[i], b[j], acc[i][j]);
        }
        __syncthreads();
    }

    #pragma unroll
    for (int i = 0; i < 4; i++) {
        int r = row0 + ty * 4 + i;
        if (r < N_NODES) {
            float4 v = make_float4(acc[i][0], acc[i][1], acc[i][2], acc[i][3]);
            *(float4*)&support[(size_t)r * NHID + tx * 4] = v;
        }
    }
}

// ---------------------------------------------------------------------------
// Scatter: agg[row[e]][f] += ew[e] * support[col[e]][f]  (atomic f32)
// ---------------------------------------------------------------------------
__global__ __launch_bounds__(256) void scatter_kernel(const int* __restrict__ row,
                                                      const int* __restrict__ col,
                                                      const float* __restrict__ ew,
                                                      const float* __restrict__ support,
                                                      float* __restrict__ agg) {
    const int t = blockIdx.x * 256 + threadIdx.x;
    const int e = t >> 6;
    const int f = t & 63;
    if (e >= N_EDGES) return;
    const int r = row[e];
    const int c = col[e];
    const float w = ew[e];
    const float v = w * support[(size_t)c * NHID + f];
    atomicAdd(&agg[(size_t)r * NHID + f], v);
}

// ---------------------------------------------------------------------------
// BN stats: per-feature sum / sumsq over nodes.
// ---------------------------------------------------------------------------
__global__ __launch_bounds__(256) void stats_kernel(const float* __restrict__ agg,
                                                    float* __restrict__ sums) {
    const int f = threadIdx.x & 63;
    const int sub = threadIdx.x >> 6;
    float s = 0.f, s2 = 0.f;
    for (int n = blockIdx.x * 4 + sub; n < N_NODES; n += gridDim.x * 4) {
        float v = agg[(size_t)n * NHID + f];
        s += v;
        s2 = fmaf(v, v, s2);
    }
    __shared__ float red[2][4][64];
    red[0][sub][f] = s;
    red[1][sub][f] = s2;
    __syncthreads();
    if (threadIdx.x < 64) {
        float ts = red[0][0][f] + red[0][1][f] + red[0][2][f] + red[0][3][f];
        atomicAdd(&sums[f], ts);
    } else if (threadIdx.x < 128) {
        float t2 = red[1][0][f] + red[1][1][f] + red[1][2][f] + red[1][3][f];
        atomicAdd(&sums[64 + f], t2);
    }
}

// ---------------------------------------------------------------------------
// Finalize: scale = gamma*rsqrt(var+eps); shift = beta - mean*scale.
// (reference's +b cancels via BN mean subtraction; b is zeros anyway)
// ---------------------------------------------------------------------------
__global__ __launch_bounds__(64) void finalize_kernel(const float* __restrict__ sums,
                                                      const float* __restrict__ gamma,
                                                      const float* __restrict__ beta,
                                                      float* __restrict__ scaleshift) {
    const int f = threadIdx.x;
    const float inv_n = 1.0f / (float)N_NODES;
    float mean = sums[f] * inv_n;
    float var = sums[64 + f] * inv_n - mean * mean;
    float sc = gamma[f] * rsqrtf(var + 1e-5f);
    scaleshift[f] = sc;
    scaleshift[64 + f] = beta[f] - mean * sc;
}

// ---------------------------------------------------------------------------
// Threefry-2x32, 20 rounds, key=(0,42). Core hand-verified vs JAX test vector
// key=(0,0), cnt=(0,0) -> (0x6b200159, 0x99ba4efe).
// ---------------------------------------------------------------------------
__device__ __forceinline__ uint32_t rotl32(uint32_t x, int d) {
    return (x << d) | (x >> (32 - d));
}

__device__ __forceinline__ void threefry2x32_0_42(uint32_t x0, uint32_t x1,
                                                  uint32_t& o0, uint32_t& o1) {
    const uint32_t k0 = 0u, k1 = 42u;
    const uint32_t k2 = k0 ^ k1 ^ 0x1BD11BDAu;
    x0 += k0; x1 += k1;
    x0 += x1; x1 = rotl32(x1, 13) ^ x0;
    x0 += x1; x1 = rotl32(x1, 15) ^ x0;
    x0 += x1; x1 = rotl32(x1, 26) ^ x0;
    x0 += x1; x1 = rotl32(x1, 6)  ^ x0;
    x0 += k1; x1 += k2 + 1u;
    x0 += x1; x1 = rotl32(x1, 17) ^ x0;
    x0 += x1; x1 = rotl32(x1, 29) ^ x0;
    x0 += x1; x1 = rotl32(x1, 16) ^ x0;
    x0 += x1; x1 = rotl32(x1, 24) ^ x0;
    x0 += k2; x1 += k0 + 2u;
    x0 += x1; x1 = rotl32(x1, 13) ^ x0;
    x0 += x1; x1 = rotl32(x1, 15) ^ x0;
    x0 += x1; x1 = rotl32(x1, 26) ^ x0;
    x0 += x1; x1 = rotl32(x1, 6)  ^ x0;
    x0 += k0; x1 += k1 + 3u;
    x0 += x1; x1 = rotl32(x1, 17) ^ x0;
    x0 += x1; x1 = rotl32(x1, 29) ^ x0;
    x0 += x1; x1 = rotl32(x1, 16) ^ x0;
    x0 += x1; x1 = rotl32(x1, 24) ^ x0;
    x0 += k1; x1 += k2 + 4u;
    x0 += x1; x1 = rotl32(x1, 13) ^ x0;
    x0 += x1; x1 = rotl32(x1, 15) ^ x0;
    x0 += x1; x1 = rotl32(x1, 26) ^ x0;
    x0 += x1; x1 = rotl32(x1, 6)  ^ x0;
    x0 += k2; x1 += k0 + 5u;
    o0 = x0; o1 = x1;
}

// ---------------------------------------------------------------------------
// Apply: BN affine + ReLU + dropout; f32 out (overwrites dead support).
// Partitionable threefry: element i -> counter (0, i), bits = o0 ^ o1.
// ---------------------------------------------------------------------------
__global__ __launch_bounds__(256) void apply_kernel(const float* __restrict__ agg,
                                                    const float* __restrict__ scaleshift,
                                                    float* __restrict__ out) {
    const int i = blockIdx.x * 256 + threadIdx.x;
    if (i >= N_ELEMS) return;
    const int f = i & 63;
    const float sc = scaleshift[f];
    const float sh = scaleshift[64 + f];

    uint32_t o0, o1;
    threefry2x32_0_42(0u, (uint32_t)i, o0, o1);
    uint32_t bits = o0 ^ o1;
    float u = __uint_as_float((bits >> 9) | 0x3F800000u) - 1.0f;

    float v = fmaxf(fmaf(agg[i], sc, sh), 0.0f);
    out[i] = (u < 0.7f) ? v * (1.0f / 0.7f) : 0.0f;
}

// ---------------------------------------------------------------------------
extern "C" void kernel_launch(void* const* d_in, const int* in_sizes, int n_in,
                              void* d_out, int out_size, void* d_ws, size_t ws_size,
                              hipStream_t stream) {
    const float* x     = (const float*)d_in[0];
    const int*   row   = (const int*)d_in[1];
    const int*   col   = (const int*)d_in[2];
    const float* ew    = (const float*)d_in[3];
    const float* W     = (const float*)d_in[4];
    // d_in[5] = b : zeros, and cancels via BN mean subtraction regardless
    const float* gamma = (const float*)d_in[6];
    const float* beta  = (const float*)d_in[7];
    float* out = (float*)d_out;

    float* sums       = (float*)d_ws;            // 128 f32
    float* scaleshift = sums + 128;              // 128 f32
    float* agg        = scaleshift + 128;        // 6.4M f32
    float* support    = out;                     // staged in d_out, dead before apply

    // Zero sums + agg. 25.601 MB total ws use.
    hipMemsetAsync(d_ws, 0, (256 + (size_t)N_ELEMS) * sizeof(float), stream);

    // GEMM -> support (f32, staged in d_out)
    int gemm_blocks = (N_NODES + 63) / 64;  // 1563
    gemm_kernel<<<gemm_blocks, 256, 0, stream>>>(x, W, support);

    // Scatter-add SpMM
    int scatter_blocks = (N_EDGES * 64) / 256;  // 400,000
    scatter_kernel<<<scatter_blocks, 256, 0, stream>>>(row, col, ew, support, agg);

    // BN stats + finalize
    stats_kernel<<<1024, 256, 0, stream>>>(agg, sums);
    finalize_kernel<<<1, 64, 0, stream>>>(sums, gamma, beta, scaleshift);

    // BN affine + ReLU + dropout -> f32 out
    int apply_blocks = (N_ELEMS + 255) / 256;  // 25,000
    apply_kernel<<<apply_blocks, 256, 0, stream>>>(agg, scaleshift, out);
}

// Round 7
// 592.308 us; speedup vs baseline: 1.0624x; 1.0624x over previous
//
#include <hip/hip_runtime.h>
#include <stdint.h>

#define N_NODES 100000
#define N_EDGES 1600000
#define NFEAT 256
#define NHID 64
#define N_ELEMS (N_NODES * NHID)   // 6,400,000

// Config (validated R6): inputs f32, output f32, dropout = JAX partitionable
// threefry (key=(0,42), counter (0,i), bits = o0^o1).
// ws: sums[128] + scaleshift[128] + agg[6.4M f32] = 25.601 MB.
// support[6.4M f32] staged in d_out (dead before apply overwrites it).

// ---------------------------------------------------------------------------
// GEMM v2: support[N x 64] = x[N x 256] @ W[256 x 64]  (f32)
// 64x64 tile, BK=64, 256 threads, 4x4 microtile.
// Inner loop k-blocked by 4: all LDS reads are ds_read_b128 (8 per 64 FMA).
// Pad 68 floats -> 272B rows, 16B-aligned for b128; 2-way read aliasing only.
// ---------------------------------------------------------------------------
__global__ __launch_bounds__(256) void gemm_kernel(const float* __restrict__ x,
                                                   const float* __restrict__ W,
                                                   float* __restrict__ support) {
    __shared__ float As[64][68];
    __shared__ float Bs[64][68];
    const int tid = threadIdx.x;
    const int row0 = blockIdx.x * 64;
    const int tx = tid & 15;        // n-dim
    const int ty = tid >> 4;        // m-dim
    const int lr = tid >> 4;        // loader row 0..15
    const int lc = (tid & 15) * 4;  // loader col 0..60

    float acc[4][4] = {};

    for (int k0 = 0; k0 < NFEAT; k0 += 64) {
        #pragma unroll
        for (int rr = 0; rr < 64; rr += 16) {
            int gr = row0 + lr + rr;
            float4 v = make_float4(0.f, 0.f, 0.f, 0.f);
            if (gr < N_NODES)
                v = *(const float4*)&x[(size_t)gr * NFEAT + k0 + lc];
            *(float4*)&As[lr + rr][lc] = v;
        }
        #pragma unroll
        for (int rr = 0; rr < 64; rr += 16) {
            int gr = k0 + lr + rr;
            *(float4*)&Bs[lr + rr][lc] = *(const float4*)&W[(size_t)gr * NHID + lc];
        }
        __syncthreads();

        #pragma unroll
        for (int kk = 0; kk < 64; kk += 4) {
            float4 b0 = *(const float4*)&Bs[kk + 0][tx * 4];
            float4 b1 = *(const float4*)&Bs[kk + 1][tx * 4];
            float4 b2 = *(const float4*)&Bs[kk + 2][tx * 4];
            float4 b3 = *(const float4*)&Bs[kk + 3][tx * 4];
            #pragma unroll
            for (int i = 0; i < 4; i++) {
                float4 a = *(const float4*)&As[ty * 4 + i][kk];
                acc[i][0] = fmaf(a.x, b0.x, acc[i][0]);
                acc[i][1] = fmaf(a.x, b0.y, acc[i][1]);
                acc[i][2] = fmaf(a.x, b0.z, acc[i][2]);
                acc[i][3] = fmaf(a.x, b0.w, acc[i][3]);
                acc[i][0] = fmaf(a.y, b1.x, acc[i][0]);
                acc[i][1] = fmaf(a.y, b1.y, acc[i][1]);
                acc[i][2] = fmaf(a.y, b1.z, acc[i][2]);
                acc[i][3] = fmaf(a.y, b1.w, acc[i][3]);
                acc[i][0] = fmaf(a.z, b2.x, acc[i][0]);
                acc[i][1] = fmaf(a.z, b2.y, acc[i][1]);
                acc[i][2] = fmaf(a.z, b2.z, acc[i][2]);
                acc[i][3] = fmaf(a.z, b2.w, acc[i][3]);
                acc[i][0] = fmaf(a.w, b3.x, acc[i][0]);
                acc[i][1] = fmaf(a.w, b3.y, acc[i][1]);
                acc[i][2] = fmaf(a.w, b3.z, acc[i][2]);
                acc[i][3] = fmaf(a.w, b3.w, acc[i][3]);
            }
        }
        __syncthreads();
    }

    #pragma unroll
    for (int i = 0; i < 4; i++) {
        int r = row0 + ty * 4 + i;
        if (r < N_NODES) {
            float4 v = make_float4(acc[i][0], acc[i][1], acc[i][2], acc[i][3]);
            *(float4*)&support[(size_t)r * NHID + tx * 4] = v;
        }
    }
}

// ---------------------------------------------------------------------------
// Scatter v2: grid-stride persistent waves; one wave per edge per iteration
// (64 lanes = 64 features). Wave-uniform edge index forced scalar via
// readfirstlane -> index loads become s_load. 2-edge unroll for MLP.
// Atomics: relaxed, agent scope -> global_atomic_add_f32, no return.
// ---------------------------------------------------------------------------
__global__ __launch_bounds__(256) void scatter_kernel(const int* __restrict__ row,
                                                      const int* __restrict__ col,
                                                      const float* __restrict__ ew,
                                                      const float* __restrict__ support,
                                                      float* __restrict__ agg) {
    const int f = threadIdx.x & 63;
    const int wid = __builtin_amdgcn_readfirstlane(blockIdx.x * 4 + (threadIdx.x >> 6));
    const int nw = gridDim.x * 4;   // total waves

    int e = wid;
    for (; e + nw < N_EDGES; e += 2 * nw) {
        const int e1 = e + nw;
        const int r0 = row[e];
        const int c0 = col[e];
        const float w0 = ew[e];
        const int r1 = row[e1];
        const int c1 = col[e1];
        const float w1 = ew[e1];
        const float v0 = w0 * support[(size_t)c0 * NHID + f];
        const float v1 = w1 * support[(size_t)c1 * NHID + f];
        __hip_atomic_fetch_add(&agg[(size_t)r0 * NHID + f], v0,
                               __ATOMIC_RELAXED, __HIP_MEMORY_SCOPE_AGENT);
        __hip_atomic_fetch_add(&agg[(size_t)r1 * NHID + f], v1,
                               __ATOMIC_RELAXED, __HIP_MEMORY_SCOPE_AGENT);
    }
    for (; e < N_EDGES; e += nw) {
        const int r0 = row[e];
        const int c0 = col[e];
        const float w0 = ew[e];
        const float v0 = w0 * support[(size_t)c0 * NHID + f];
        __hip_atomic_fetch_add(&agg[(size_t)r0 * NHID + f], v0,
                               __ATOMIC_RELAXED, __HIP_MEMORY_SCOPE_AGENT);
    }
}

// ---------------------------------------------------------------------------
// BN stats: per-feature sum / sumsq over nodes.
// ---------------------------------------------------------------------------
__global__ __launch_bounds__(256) void stats_kernel(const float* __restrict__ agg,
                                                    float* __restrict__ sums) {
    const int f = threadIdx.x & 63;
    const int sub = threadIdx.x >> 6;
    float s = 0.f, s2 = 0.f;
    for (int n = blockIdx.x * 4 + sub; n < N_NODES; n += gridDim.x * 4) {
        float v = agg[(size_t)n * NHID + f];
        s += v;
        s2 = fmaf(v, v, s2);
    }
    __shared__ float red[2][4][64];
    red[0][sub][f] = s;
    red[1][sub][f] = s2;
    __syncthreads();
    if (threadIdx.x < 64) {
        float ts = red[0][0][f] + red[0][1][f] + red[0][2][f] + red[0][3][f];
        atomicAdd(&sums[f], ts);
    } else if (threadIdx.x < 128) {
        float t2 = red[1][0][f] + red[1][1][f] + red[1][2][f] + red[1][3][f];
        atomicAdd(&sums[64 + f], t2);
    }
}

// ---------------------------------------------------------------------------
// Finalize: scale = gamma*rsqrt(var+eps); shift = beta - mean*scale.
// (reference's +b cancels via BN mean subtraction; b is zeros anyway)
// ---------------------------------------------------------------------------
__global__ __launch_bounds__(64) void finalize_kernel(const float* __restrict__ sums,
                                                      const float* __restrict__ gamma,
                                                      const float* __restrict__ beta,
                                                      float* __restrict__ scaleshift) {
    const int f = threadIdx.x;
    const float inv_n = 1.0f / (float)N_NODES;
    float mean = sums[f] * inv_n;
    float var = sums[64 + f] * inv_n - mean * mean;
    float sc = gamma[f] * rsqrtf(var + 1e-5f);
    scaleshift[f] = sc;
    scaleshift[64 + f] = beta[f] - mean * sc;
}

// ---------------------------------------------------------------------------
// Threefry-2x32, 20 rounds, key=(0,42). Hand-verified vs JAX test vector.
// ---------------------------------------------------------------------------
__device__ __forceinline__ uint32_t rotl32(uint32_t x, int d) {
    return (x << d) | (x >> (32 - d));
}

__device__ __forceinline__ void threefry2x32_0_42(uint32_t x0, uint32_t x1,
                                                  uint32_t& o0, uint32_t& o1) {
    const uint32_t k0 = 0u, k1 = 42u;
    const uint32_t k2 = k0 ^ k1 ^ 0x1BD11BDAu;
    x0 += k0; x1 += k1;
    x0 += x1; x1 = rotl32(x1, 13) ^ x0;
    x0 += x1; x1 = rotl32(x1, 15) ^ x0;
    x0 += x1; x1 = rotl32(x1, 26) ^ x0;
    x0 += x1; x1 = rotl32(x1, 6)  ^ x0;
    x0 += k1; x1 += k2 + 1u;
    x0 += x1; x1 = rotl32(x1, 17) ^ x0;
    x0 += x1; x1 = rotl32(x1, 29) ^ x0;
    x0 += x1; x1 = rotl32(x1, 16) ^ x0;
    x0 += x1; x1 = rotl32(x1, 24) ^ x0;
    x0 += k2; x1 += k0 + 2u;
    x0 += x1; x1 = rotl32(x1, 13) ^ x0;
    x0 += x1; x1 = rotl32(x1, 15) ^ x0;
    x0 += x1; x1 = rotl32(x1, 26) ^ x0;
    x0 += x1; x1 = rotl32(x1, 6)  ^ x0;
    x0 += k0; x1 += k1 + 3u;
    x0 += x1; x1 = rotl32(x1, 17) ^ x0;
    x0 += x1; x1 = rotl32(x1, 29) ^ x0;
    x0 += x1; x1 = rotl32(x1, 16) ^ x0;
    x0 += x1; x1 = rotl32(x1, 24) ^ x0;
    x0 += k1; x1 += k2 + 4u;
    x0 += x1; x1 = rotl32(x1, 13) ^ x0;
    x0 += x1; x1 = rotl32(x1, 15) ^ x0;
    x0 += x1; x1 = rotl32(x1, 26) ^ x0;
    x0 += x1; x1 = rotl32(x1, 6)  ^ x0;
    x0 += k2; x1 += k0 + 5u;
    o0 = x0; o1 = x1;
}

// ---------------------------------------------------------------------------
// Apply: BN affine + ReLU + dropout; f32 out (overwrites dead support).
// ---------------------------------------------------------------------------
__global__ __launch_bounds__(256) void apply_kernel(const float* __restrict__ agg,
                                                    const float* __restrict__ scaleshift,
                                                    float* __restrict__ out) {
    const int i = blockIdx.x * 256 + threadIdx.x;
    if (i >= N_ELEMS) return;
    const int f = i & 63;
    const float sc = scaleshift[f];
    const float sh = scaleshift[64 + f];

    uint32_t o0, o1;
    threefry2x32_0_42(0u, (uint32_t)i, o0, o1);
    uint32_t bits = o0 ^ o1;
    float u = __uint_as_float((bits >> 9) | 0x3F800000u) - 1.0f;

    float v = fmaxf(fmaf(agg[i], sc, sh), 0.0f);
    out[i] = (u < 0.7f) ? v * (1.0f / 0.7f) : 0.0f;
}

// ---------------------------------------------------------------------------
extern "C" void kernel_launch(void* const* d_in, const int* in_sizes, int n_in,
                              void* d_out, int out_size, void* d_ws, size_t ws_size,
                              hipStream_t stream) {
    const float* x     = (const float*)d_in[0];
    const int*   row   = (const int*)d_in[1];
    const int*   col   = (const int*)d_in[2];
    const float* ew    = (const float*)d_in[3];
    const float* W     = (const float*)d_in[4];
    const float* gamma = (const float*)d_in[6];
    const float* beta  = (const float*)d_in[7];
    float* out = (float*)d_out;

    float* sums       = (float*)d_ws;            // 128 f32
    float* scaleshift = sums + 128;              // 128 f32
    float* agg        = scaleshift + 128;        // 6.4M f32
    float* support    = out;                     // staged in d_out, dead before apply

    hipMemsetAsync(d_ws, 0, (256 + (size_t)N_ELEMS) * sizeof(float), stream);

    // GEMM -> support (f32, staged in d_out)
    int gemm_blocks = (N_NODES + 63) / 64;  // 1563
    gemm_kernel<<<gemm_blocks, 256, 0, stream>>>(x, W, support);

    // Scatter-add SpMM: persistent grid-stride waves
    scatter_kernel<<<2048, 256, 0, stream>>>(row, col, ew, support, agg);

    // BN stats + finalize
    stats_kernel<<<1024, 256, 0, stream>>>(agg, sums);
    finalize_kernel<<<1, 64, 0, stream>>>(sums, gamma, beta, scaleshift);

    // BN affine + ReLU + dropout -> f32 out
    int apply_blocks = (N_ELEMS + 255) / 256;  // 25,000
    apply_kernel<<<apply_blocks, 256, 0, stream>>>(agg, scaleshift, out);
}

// Round 8
// 514.120 us; speedup vs baseline: 1.2240x; 1.1521x over previous
//
#include <hip/hip_runtime.h>
#include <stdint.h>

#define N_NODES 100000
#define N_EDGES 1600000
#define NFEAT 256
#define NHID 64
#define N_ELEMS (N_NODES * NHID)   // 6,400,000
#define NBLK 391                   // ceil(N_NODES/256) for scan kernels

// Config (validated R6/R7): inputs f32, output f32, dropout = JAX partitionable
// threefry (key=(0,42), counter (0,i), bits = o0^o1).
//
// R7 lesson: scatter atomics hit the TCC f32-atomic ceiling (303G/s, write-
// through 4B each). This round builds CSR on-device and gather-reduces with
// ZERO f32 atomics. GEMM moved to bf16 MFMA (2% threshold >> bf16 noise).
//
// ws layout (39.6 MB total; R1 proved >=51.2MB works):
//   sums[128] f32 | scaleshift[128] f32 | cnt[100000] i32 | rowptr[100002] i32
//   | cursor[100000] i32 | bsum[512] i32 | wt[16384] ushort | agg[6.4M] f32
//   | sorted[1.6M] int2
// support[6.4M] f32 staged in d_out (dead before apply overwrites).

typedef __attribute__((ext_vector_type(8))) short bf16x8;
typedef __attribute__((ext_vector_type(4))) float f32x4;

__device__ __forceinline__ unsigned short f2bf(float f) {
    uint32_t u = __float_as_uint(f);
    u += 0x7FFFu + ((u >> 16) & 1u);   // RNE
    return (unsigned short)(u >> 16);
}

// ---------------------------------------------------------------------------
// W^T prep: wt[n][k] = bf16(W[k][n])  (16384 elements)
// ---------------------------------------------------------------------------
__global__ __launch_bounds__(256) void wtprep_kernel(const float* __restrict__ W,
                                                     unsigned short* __restrict__ wt) {
    int i = blockIdx.x * 256 + threadIdx.x;
    if (i < NFEAT * NHID) {
        int k = i >> 6, n = i & 63;
        wt[n * NFEAT + k] = f2bf(W[i]);
    }
}

// ---------------------------------------------------------------------------
// GEMM (MFMA bf16): support[N x 64] = x[N x 256] @ W[256 x 64], f32 out.
// 64-row tile per block, whole K=256 staged once in LDS (x converted to bf16,
// W^T preconverted). 4 waves x 4 n-tiles of mfma_f32_16x16x32_bf16.
// ---------------------------------------------------------------------------
__global__ __launch_bounds__(256) void gemm_kernel(const float* __restrict__ x,
                                                   const unsigned short* __restrict__ wt,
                                                   float* __restrict__ support) {
    __shared__ unsigned short Abf[64][264];  // row stride 528B (16B-aligned)
    __shared__ unsigned short Bt[64][264];   // Bt[n][k]
    const int t = threadIdx.x;
    const int row0 = blockIdx.x * 64;

    // Stage A (x rows, f32 -> bf16): 16 iters x (4 rows x 64 float4)
    {
        const int r = t >> 6;     // 0..3
        const int c4 = t & 63;    // float4 column
        #pragma unroll
        for (int rr = 0; rr < 16; rr++) {
            int lr_ = rr * 4 + r;
            int gr = row0 + lr_;
            float4 v = make_float4(0.f, 0.f, 0.f, 0.f);
            if (gr < N_NODES) v = *(const float4*)&x[(size_t)gr * NFEAT + c4 * 4];
            ushort4 u;
            u.x = f2bf(v.x); u.y = f2bf(v.y); u.z = f2bf(v.z); u.w = f2bf(v.w);
            *(ushort4*)&Abf[lr_][c4 * 4] = u;
        }
    }
    // Stage Bt from global wt (already bf16 + transposed): 8 iters x 16B chunks
    {
        const int rB = t >> 5;    // 0..7
        const int ch = t & 31;    // 16B chunk within row
        #pragma unroll
        for (int rr = 0; rr < 8; rr++) {
            int n = rr * 8 + rB;
            uint4 v = *(const uint4*)&wt[n * NFEAT + ch * 8];
            *(uint4*)&Bt[n][ch * 8] = v;
        }
    }
    __syncthreads();

    const int lane = t & 63;
    const int w = t >> 6;
    const int m = lane & 15;
    const int q = lane >> 4;
    f32x4 acc0 = {0.f, 0.f, 0.f, 0.f};
    f32x4 acc1 = acc0, acc2 = acc0, acc3 = acc0;

    #pragma unroll
    for (int ks = 0; ks < NFEAT; ks += 32) {
        bf16x8 af = *(const bf16x8*)&Abf[w * 16 + m][ks + q * 8];
        bf16x8 b0 = *(const bf16x8*)&Bt[ 0 + m][ks + q * 8];
        bf16x8 b1 = *(const bf16x8*)&Bt[16 + m][ks + q * 8];
        bf16x8 b2 = *(const bf16x8*)&Bt[32 + m][ks + q * 8];
        bf16x8 b3 = *(const bf16x8*)&Bt[48 + m][ks + q * 8];
        acc0 = __builtin_amdgcn_mfma_f32_16x16x32_bf16(af, b0, acc0, 0, 0, 0);
        acc1 = __builtin_amdgcn_mfma_f32_16x16x32_bf16(af, b1, acc1, 0, 0, 0);
        acc2 = __builtin_amdgcn_mfma_f32_16x16x32_bf16(af, b2, acc2, 0, 0, 0);
        acc3 = __builtin_amdgcn_mfma_f32_16x16x32_bf16(af, b3, acc3, 0, 0, 0);
    }

    // C/D layout: row = q*4 + reg, col = nt*16 + m  (guide §3, m89-verified)
    #pragma unroll
    for (int reg = 0; reg < 4; reg++) {
        int grow = row0 + w * 16 + q * 4 + reg;
        if (grow < N_NODES) {
            support[(size_t)grow * NHID +  0 + m] = acc0[reg];
            support[(size_t)grow * NHID + 16 + m] = acc1[reg];
            support[(size_t)grow * NHID + 32 + m] = acc2[reg];
            support[(size_t)grow * NHID + 48 + m] = acc3[reg];
        }
    }
}

// ---------------------------------------------------------------------------
// CSR build step 1: histogram of row indices.
// ---------------------------------------------------------------------------
__global__ __launch_bounds__(256) void hist_kernel(const int* __restrict__ row,
                                                   int* __restrict__ cnt) {
    for (int e = blockIdx.x * 256 + threadIdx.x; e < N_EDGES; e += gridDim.x * 256)
        atomicAdd(&cnt[row[e]], 1);
}

// ---------------------------------------------------------------------------
// CSR build step 2a: per-block exclusive scan + block sums.
// ---------------------------------------------------------------------------
__global__ __launch_bounds__(256) void scan1_kernel(const int* __restrict__ cnt,
                                                    int* __restrict__ rowptr,
                                                    int* __restrict__ bsum) {
    __shared__ int s[256];
    const int t = threadIdx.x;
    const int i = blockIdx.x * 256 + t;
    int v = (i < N_NODES) ? cnt[i] : 0;
    s[t] = v;
    __syncthreads();
    #pragma unroll
    for (int off = 1; off < 256; off <<= 1) {
        int u = (t >= off) ? s[t - off] : 0;
        __syncthreads();
        s[t] += u;
        __syncthreads();
    }
    if (i < N_NODES) rowptr[i] = s[t] - v;   // local exclusive
    if (t == 255) bsum[blockIdx.x] = s[t];
}

// ---------------------------------------------------------------------------
// CSR build step 2b: exclusive scan of NBLK block sums (single block).
// ---------------------------------------------------------------------------
__global__ __launch_bounds__(512) void scan2_kernel(int* __restrict__ bsum) {
    __shared__ int s[512];
    const int t = threadIdx.x;
    int v = (t < NBLK) ? bsum[t] : 0;
    s[t] = v;
    __syncthreads();
    #pragma unroll
    for (int off = 1; off < 512; off <<= 1) {
        int u = (t >= off) ? s[t - off] : 0;
        __syncthreads();
        s[t] += u;
        __syncthreads();
    }
    if (t < NBLK) bsum[t] = s[t] - v;
}

// ---------------------------------------------------------------------------
// CSR build step 2c: add block offsets; init cursor; close rowptr.
// ---------------------------------------------------------------------------
__global__ __launch_bounds__(256) void scan3_kernel(int* __restrict__ rowptr,
                                                    int* __restrict__ cursor,
                                                    const int* __restrict__ bsum) {
    const int i = blockIdx.x * 256 + threadIdx.x;
    if (i < N_NODES) {
        int v = rowptr[i] + bsum[blockIdx.x];
        rowptr[i] = v;
        cursor[i] = v;
    }
    if (i == 0) rowptr[N_NODES] = N_EDGES;
}

// ---------------------------------------------------------------------------
// CSR build step 3: bin edges into row-sorted (col, weight) records.
// ---------------------------------------------------------------------------
__global__ __launch_bounds__(256) void bin_kernel(const int* __restrict__ row,
                                                  const int* __restrict__ col,
                                                  const float* __restrict__ ew,
                                                  int* __restrict__ cursor,
                                                  int2* __restrict__ sorted) {
    for (int e = blockIdx.x * 256 + threadIdx.x; e < N_EDGES; e += gridDim.x * 256) {
        int r = row[e];
        int pos = atomicAdd(&cursor[r], 1);
        sorted[pos] = make_int2(col[e], __float_as_int(ew[e]));
    }
}

// ---------------------------------------------------------------------------
// Gather-reduce: agg[n][f] = sum_{e in row n} w_e * support[col_e][f].
// One wave per node (lane = feature). NO f32 atomics. BN stats fused:
// per-wave running sum/sumsq -> block LDS reduce -> 128 atomics per block.
// ---------------------------------------------------------------------------
__global__ __launch_bounds__(256) void gather_kernel(const int* __restrict__ rowptr,
                                                     const int2* __restrict__ sorted,
                                                     const float* __restrict__ support,
                                                     float* __restrict__ agg,
                                                     float* __restrict__ sums) {
    const int f = threadIdx.x & 63;
    const int wv = threadIdx.x >> 6;
    const int wid = blockIdx.x * 4 + wv;
    const int nw = gridDim.x * 4;
    float s = 0.f, s2 = 0.f;

    for (int n = wid; n < N_NODES; n += nw) {
        const int jb = __builtin_amdgcn_readfirstlane(rowptr[n]);
        const int je = __builtin_amdgcn_readfirstlane(rowptr[n + 1]);
        float acc = 0.f;
        int j = jb;
        for (; j + 4 <= je; j += 4) {
            int2 a0 = sorted[j + 0];
            int2 a1 = sorted[j + 1];
            int2 a2 = sorted[j + 2];
            int2 a3 = sorted[j + 3];
            int c0 = __builtin_amdgcn_readfirstlane(a0.x);
            int c1 = __builtin_amdgcn_readfirstlane(a1.x);
            int c2 = __builtin_amdgcn_readfirstlane(a2.x);
            int c3 = __builtin_amdgcn_readfirstlane(a3.x);
            float w0 = __uint_as_float(__builtin_amdgcn_readfirstlane(a0.y));
            float w1 = __uint_as_float(__builtin_amdgcn_readfirstlane(a1.y));
            float w2 = __uint_as_float(__builtin_amdgcn_readfirstlane(a2.y));
            float w3 = __uint_as_float(__builtin_amdgcn_readfirstlane(a3.y));
            float v0 = support[c0 * NHID + f];
            float v1 = support[c1 * NHID + f];
            float v2 = support[c2 * NHID + f];
            float v3 = support[c3 * NHID + f];
            acc = fmaf(w0, v0, acc);
            acc = fmaf(w1, v1, acc);
            acc = fmaf(w2, v2, acc);
            acc = fmaf(w3, v3, acc);
        }
        for (; j < je; ++j) {
            int2 a = sorted[j];
            int c = __builtin_amdgcn_readfirstlane(a.x);
            float wgt = __uint_as_float(__builtin_amdgcn_readfirstlane(a.y));
            acc = fmaf(wgt, support[c * NHID + f], acc);
        }
        agg[(size_t)n * NHID + f] = acc;
        s += acc;
        s2 = fmaf(acc, acc, s2);
    }

    __shared__ float red[2][4][64];
    red[0][wv][f] = s;
    red[1][wv][f] = s2;
    __syncthreads();
    if (threadIdx.x < 64) {
        atomicAdd(&sums[f], red[0][0][f] + red[0][1][f] + red[0][2][f] + red[0][3][f]);
    } else if (threadIdx.x < 128) {
        atomicAdd(&sums[64 + f], red[1][0][f] + red[1][1][f] + red[1][2][f] + red[1][3][f]);
    }
}

// ---------------------------------------------------------------------------
// Finalize: scale = gamma*rsqrt(var+eps); shift = beta - mean*scale.
// (reference's +b cancels via BN mean subtraction; b is zeros anyway)
// ---------------------------------------------------------------------------
__global__ __launch_bounds__(64) void finalize_kernel(const float* __restrict__ sums,
                                                      const float* __restrict__ gamma,
                                                      const float* __restrict__ beta,
                                                      float* __restrict__ scaleshift) {
    const int f = threadIdx.x;
    const float inv_n = 1.0f / (float)N_NODES;
    float mean = sums[f] * inv_n;
    float var = sums[64 + f] * inv_n - mean * mean;
    float sc = gamma[f] * rsqrtf(var + 1e-5f);
    scaleshift[f] = sc;
    scaleshift[64 + f] = beta[f] - mean * sc;
}

// ---------------------------------------------------------------------------
// Threefry-2x32, 20 rounds, key=(0,42). Hand-verified vs JAX test vector.
// ---------------------------------------------------------------------------
__device__ __forceinline__ uint32_t rotl32(uint32_t x, int d) {
    return (x << d) | (x >> (32 - d));
}

__device__ __forceinline__ void threefry2x32_0_42(uint32_t x0, uint32_t x1,
                                                  uint32_t& o0, uint32_t& o1) {
    const uint32_t k0 = 0u, k1 = 42u;
    const uint32_t k2 = k0 ^ k1 ^ 0x1BD11BDAu;
    x0 += k0; x1 += k1;
    x0 += x1; x1 = rotl32(x1, 13) ^ x0;
    x0 += x1; x1 = rotl32(x1, 15) ^ x0;
    x0 += x1; x1 = rotl32(x1, 26) ^ x0;
    x0 += x1; x1 = rotl32(x1, 6)  ^ x0;
    x0 += k1; x1 += k2 + 1u;
    x0 += x1; x1 = rotl32(x1, 17) ^ x0;
    x0 += x1; x1 = rotl32(x1, 29) ^ x0;
    x0 += x1; x1 = rotl32(x1, 16) ^ x0;
    x0 += x1; x1 = rotl32(x1, 24) ^ x0;
    x0 += k2; x1 += k0 + 2u;
    x0 += x1; x1 = rotl32(x1, 13) ^ x0;
    x0 += x1; x1 = rotl32(x1, 15) ^ x0;
    x0 += x1; x1 = rotl32(x1, 26) ^ x0;
    x0 += x1; x1 = rotl32(x1, 6)  ^ x0;
    x0 += k0; x1 += k1 + 3u;
    x0 += x1; x1 = rotl32(x1, 17) ^ x0;
    x0 += x1; x1 = rotl32(x1, 29) ^ x0;
    x0 += x1; x1 = rotl32(x1, 16) ^ x0;
    x0 += x1; x1 = rotl32(x1, 24) ^ x0;
    x0 += k1; x1 += k2 + 4u;
    x0 += x1; x1 = rotl32(x1, 13) ^ x0;
    x0 += x1; x1 = rotl32(x1, 15) ^ x0;
    x0 += x1; x1 = rotl32(x1, 26) ^ x0;
    x0 += x1; x1 = rotl32(x1, 6)  ^ x0;
    x0 += k2; x1 += k0 + 5u;
    o0 = x0; o1 = x1;
}

// ---------------------------------------------------------------------------
// Apply: BN affine + ReLU + dropout; f32 out (overwrites dead support).
// ---------------------------------------------------------------------------
__global__ __launch_bounds__(256) void apply_kernel(const float* __restrict__ agg,
                                                    const float* __restrict__ scaleshift,
                                                    float* __restrict__ out) {
    const int i = blockIdx.x * 256 + threadIdx.x;
    if (i >= N_ELEMS) return;
    const int f = i & 63;
    const float sc = scaleshift[f];
    const float sh = scaleshift[64 + f];

    uint32_t o0, o1;
    threefry2x32_0_42(0u, (uint32_t)i, o0, o1);
    uint32_t bits = o0 ^ o1;
    float u = __uint_as_float((bits >> 9) | 0x3F800000u) - 1.0f;

    float v = fmaxf(fmaf(agg[i], sc, sh), 0.0f);
    out[i] = (u < 0.7f) ? v * (1.0f / 0.7f) : 0.0f;
}

// ---------------------------------------------------------------------------
extern "C" void kernel_launch(void* const* d_in, const int* in_sizes, int n_in,
                              void* d_out, int out_size, void* d_ws, size_t ws_size,
                              hipStream_t stream) {
    const float* x     = (const float*)d_in[0];
    const int*   row   = (const int*)d_in[1];
    const int*   col   = (const int*)d_in[2];
    const float* ew    = (const float*)d_in[3];
    const float* W     = (const float*)d_in[4];
    const float* gamma = (const float*)d_in[6];
    const float* beta  = (const float*)d_in[7];
    float* out = (float*)d_out;

    // ws layout (all offsets keep 8B alignment for int2 sorted)
    float* sums       = (float*)d_ws;                      // 128
    float* scaleshift = sums + 128;                        // 128
    int*   cnt        = (int*)(scaleshift + 128);          // 100000
    int*   rowptr     = cnt + N_NODES;                     // 100002 (padded even)
    int*   cursor     = rowptr + (N_NODES + 2);            // 100000
    int*   bsum       = cursor + N_NODES;                  // 512
    unsigned short* wt = (unsigned short*)(bsum + 512);    // 16384 ushort
    float* agg        = (float*)(wt + 16384);              // 6.4M f32
    int2*  sorted     = (int2*)(agg + (size_t)N_ELEMS);    // 1.6M int2
    float* support    = out;                               // staged in d_out

    // Zero sums + scaleshift + cnt in one shot (401 KB)
    hipMemsetAsync(d_ws, 0, (size_t)(128 + 128 + N_NODES) * sizeof(float), stream);

    // W^T -> bf16
    wtprep_kernel<<<64, 256, 0, stream>>>(W, wt);

    // GEMM (MFMA bf16) -> support (f32, in d_out)
    gemm_kernel<<<(N_NODES + 63) / 64, 256, 0, stream>>>(x, wt, support);

    // CSR build
    hist_kernel<<<1024, 256, 0, stream>>>(row, cnt);
    scan1_kernel<<<NBLK, 256, 0, stream>>>(cnt, rowptr, bsum);
    scan2_kernel<<<1, 512, 0, stream>>>(bsum);
    scan3_kernel<<<NBLK, 256, 0, stream>>>(rowptr, cursor, bsum);
    bin_kernel<<<1024, 256, 0, stream>>>(row, col, ew, cursor, sorted);

    // Gather-reduce (no f32 atomics) + fused BN stats
    gather_kernel<<<2048, 256, 0, stream>>>(rowptr, sorted, support, agg, sums);

    // BN finalize, then affine+ReLU+dropout -> f32 out
    finalize_kernel<<<1, 64, 0, stream>>>(sums, gamma, beta, scaleshift);
    apply_kernel<<<(N_ELEMS + 255) / 256, 256, 0, stream>>>(agg, scaleshift, out);
}

// Round 9
// 476.158 us; speedup vs baseline: 1.3215x; 1.0797x over previous
//
#include <hip/hip_runtime.h>
#include <stdint.h>

#define N_NODES 100000
#define N_EDGES 1600000
#define NFEAT 256
#define NHID 64
#define N_ELEMS (N_NODES * NHID)   // 6,400,000
#define NBLK 391                   // ceil(N_NODES/256) for scan kernels

// Config (validated R6/R7): inputs f32, output f32, dropout = JAX partitionable
// threefry (key=(0,42), counter (0,i), bits = o0^o1).
//
// R7: feature-space f32 atomics hit TCC ceiling (303G/s) -> CSR + gather (R8).
// R8: bin_kernel latency-bound (VALUBusy 0.3%, occ 40%): grid-stride serial
//     atomic->store chains. R9: one thread per edge (pure TLP) + bf16 support
//     (halves gather traffic + L2 footprint; 2% threshold >> bf16 noise).
//
// ws layout (39.6 MB):
//   sums[128] f32 | scaleshift[128] f32 | cnt[100000] i32 | rowptr[100002] i32
//   | cursor[100000] i32 | bsum[512] i32 | wt[16384] ushort | agg[6.4M] f32
//   | sorted[1.6M] int2
// support[6.4M] bf16 staged in d_out (dead before apply overwrites).

typedef __attribute__((ext_vector_type(8))) short bf16x8;
typedef __attribute__((ext_vector_type(4))) float f32x4;

__device__ __forceinline__ unsigned short f2bf(float f) {
    uint32_t u = __float_as_uint(f);
    u += 0x7FFFu + ((u >> 16) & 1u);   // RNE
    return (unsigned short)(u >> 16);
}
__device__ __forceinline__ float bf2f(unsigned short u) {
    return __uint_as_float(((uint32_t)u) << 16);
}

// ---------------------------------------------------------------------------
// W^T prep: wt[n][k] = bf16(W[k][n])
// ---------------------------------------------------------------------------
__global__ __launch_bounds__(256) void wtprep_kernel(const float* __restrict__ W,
                                                     unsigned short* __restrict__ wt) {
    int i = blockIdx.x * 256 + threadIdx.x;
    if (i < NFEAT * NHID) {
        int k = i >> 6, n = i & 63;
        wt[n * NFEAT + k] = f2bf(W[i]);
    }
}

// ---------------------------------------------------------------------------
// GEMM (MFMA bf16): support[N x 64] = x[N x 256] @ W[256 x 64], bf16 out.
// 64-row tile, whole K=256 in LDS, 4 waves x 4 n-tiles of 16x16x32 MFMA.
// ---------------------------------------------------------------------------
__global__ __launch_bounds__(256) void gemm_kernel(const float* __restrict__ x,
                                                   const unsigned short* __restrict__ wt,
                                                   unsigned short* __restrict__ support) {
    __shared__ unsigned short Abf[64][264];  // row stride 528B, 16B-aligned
    __shared__ unsigned short Bt[64][264];   // Bt[n][k]
    const int t = threadIdx.x;
    const int row0 = blockIdx.x * 64;

    {
        const int r = t >> 6;
        const int c4 = t & 63;
        #pragma unroll
        for (int rr = 0; rr < 16; rr++) {
            int lr_ = rr * 4 + r;
            int gr = row0 + lr_;
            float4 v = make_float4(0.f, 0.f, 0.f, 0.f);
            if (gr < N_NODES) v = *(const float4*)&x[(size_t)gr * NFEAT + c4 * 4];
            ushort4 u;
            u.x = f2bf(v.x); u.y = f2bf(v.y); u.z = f2bf(v.z); u.w = f2bf(v.w);
            *(ushort4*)&Abf[lr_][c4 * 4] = u;
        }
    }
    {
        const int rB = t >> 5;
        const int ch = t & 31;
        #pragma unroll
        for (int rr = 0; rr < 8; rr++) {
            int n = rr * 8 + rB;
            uint4 v = *(const uint4*)&wt[n * NFEAT + ch * 8];
            *(uint4*)&Bt[n][ch * 8] = v;
        }
    }
    __syncthreads();

    const int lane = t & 63;
    const int w = t >> 6;
    const int m = lane & 15;
    const int q = lane >> 4;
    f32x4 acc0 = {0.f, 0.f, 0.f, 0.f};
    f32x4 acc1 = acc0, acc2 = acc0, acc3 = acc0;

    #pragma unroll
    for (int ks = 0; ks < NFEAT; ks += 32) {
        bf16x8 af = *(const bf16x8*)&Abf[w * 16 + m][ks + q * 8];
        bf16x8 b0 = *(const bf16x8*)&Bt[ 0 + m][ks + q * 8];
        bf16x8 b1 = *(const bf16x8*)&Bt[16 + m][ks + q * 8];
        bf16x8 b2 = *(const bf16x8*)&Bt[32 + m][ks + q * 8];
        bf16x8 b3 = *(const bf16x8*)&Bt[48 + m][ks + q * 8];
        acc0 = __builtin_amdgcn_mfma_f32_16x16x32_bf16(af, b0, acc0, 0, 0, 0);
        acc1 = __builtin_amdgcn_mfma_f32_16x16x32_bf16(af, b1, acc1, 0, 0, 0);
        acc2 = __builtin_amdgcn_mfma_f32_16x16x32_bf16(af, b2, acc2, 0, 0, 0);
        acc3 = __builtin_amdgcn_mfma_f32_16x16x32_bf16(af, b3, acc3, 0, 0, 0);
    }

    // C/D layout: row = q*4 + reg, col = nt*16 + m
    #pragma unroll
    for (int reg = 0; reg < 4; reg++) {
        int grow = row0 + w * 16 + q * 4 + reg;
        if (grow < N_NODES) {
            support[(size_t)grow * NHID +  0 + m] = f2bf(acc0[reg]);
            support[(size_t)grow * NHID + 16 + m] = f2bf(acc1[reg]);
            support[(size_t)grow * NHID + 32 + m] = f2bf(acc2[reg]);
            support[(size_t)grow * NHID + 48 + m] = f2bf(acc3[reg]);
        }
    }
}

// ---------------------------------------------------------------------------
// CSR step 1: histogram. One thread per edge (pure TLP, fire-and-forget).
// ---------------------------------------------------------------------------
__global__ __launch_bounds__(256) void hist_kernel(const int* __restrict__ row,
                                                   int* __restrict__ cnt) {
    int e = blockIdx.x * 256 + threadIdx.x;
    if (e < N_EDGES) atomicAdd(&cnt[row[e]], 1);
}

// ---------------------------------------------------------------------------
// CSR step 2a: per-block exclusive scan + block sums.
// ---------------------------------------------------------------------------
__global__ __launch_bounds__(256) void scan1_kernel(const int* __restrict__ cnt,
                                                    int* __restrict__ rowptr,
                                                    int* __restrict__ bsum) {
    __shared__ int s[256];
    const int t = threadIdx.x;
    const int i = blockIdx.x * 256 + t;
    int v = (i < N_NODES) ? cnt[i] : 0;
    s[t] = v;
    __syncthreads();
    #pragma unroll
    for (int off = 1; off < 256; off <<= 1) {
        int u = (t >= off) ? s[t - off] : 0;
        __syncthreads();
        s[t] += u;
        __syncthreads();
    }
    if (i < N_NODES) rowptr[i] = s[t] - v;
    if (t == 255) bsum[blockIdx.x] = s[t];
}

// ---------------------------------------------------------------------------
// CSR step 2b: exclusive scan of NBLK block sums (single block).
// ---------------------------------------------------------------------------
__global__ __launch_bounds__(512) void scan2_kernel(int* __restrict__ bsum) {
    __shared__ int s[512];
    const int t = threadIdx.x;
    int v = (t < NBLK) ? bsum[t] : 0;
    s[t] = v;
    __syncthreads();
    #pragma unroll
    for (int off = 1; off < 512; off <<= 1) {
        int u = (t >= off) ? s[t - off] : 0;
        __syncthreads();
        s[t] += u;
        __syncthreads();
    }
    if (t < NBLK) bsum[t] = s[t] - v;
}

// ---------------------------------------------------------------------------
// CSR step 2c: add block offsets; init cursor; close rowptr.
// ---------------------------------------------------------------------------
__global__ __launch_bounds__(256) void scan3_kernel(int* __restrict__ rowptr,
                                                    int* __restrict__ cursor,
                                                    const int* __restrict__ bsum) {
    const int i = blockIdx.x * 256 + threadIdx.x;
    if (i < N_NODES) {
        int v = rowptr[i] + bsum[blockIdx.x];
        rowptr[i] = v;
        cursor[i] = v;
    }
    if (i == 0) rowptr[N_NODES] = N_EDGES;
}

// ---------------------------------------------------------------------------
// CSR step 3: bin edges into row-grouped (col, weight) records.
// One thread per edge — single independent load->atomic->store chain each.
// ---------------------------------------------------------------------------
__global__ __launch_bounds__(256) void bin_kernel(const int* __restrict__ row,
                                                  const int* __restrict__ col,
                                                  const float* __restrict__ ew,
                                                  int* __restrict__ cursor,
                                                  int2* __restrict__ sorted) {
    int e = blockIdx.x * 256 + threadIdx.x;
    if (e >= N_EDGES) return;
    int r = row[e];
    int c = col[e];
    float w = ew[e];
    int pos = atomicAdd(&cursor[r], 1);
    sorted[pos] = make_int2(c, __float_as_int(w));
}

// ---------------------------------------------------------------------------
// Gather-reduce: agg[n][f] = sum_{e in row n} w_e * support[col_e][f].
// One wave per node (lane = feature), bf16 support, f32 accumulate.
// BN stats fused: block LDS reduce -> 128 atomics per block.
// ---------------------------------------------------------------------------
__global__ __launch_bounds__(256) void gather_kernel(const int* __restrict__ rowptr,
                                                     const int2* __restrict__ sorted,
                                                     const unsigned short* __restrict__ support,
                                                     float* __restrict__ agg,
                                                     float* __restrict__ sums) {
    const int f = threadIdx.x & 63;
    const int wv = threadIdx.x >> 6;
    const int wid = blockIdx.x * 4 + wv;
    const int nw = gridDim.x * 4;
    float s = 0.f, s2 = 0.f;

    for (int n = wid; n < N_NODES; n += nw) {
        const int jb = __builtin_amdgcn_readfirstlane(rowptr[n]);
        const int je = __builtin_amdgcn_readfirstlane(rowptr[n + 1]);
        float acc = 0.f;
        int j = jb;
        for (; j + 4 <= je; j += 4) {
            int2 a0 = sorted[j + 0];
            int2 a1 = sorted[j + 1];
            int2 a2 = sorted[j + 2];
            int2 a3 = sorted[j + 3];
            int c0 = __builtin_amdgcn_readfirstlane(a0.x);
            int c1 = __builtin_amdgcn_readfirstlane(a1.x);
            int c2 = __builtin_amdgcn_readfirstlane(a2.x);
            int c3 = __builtin_amdgcn_readfirstlane(a3.x);
            float w0 = __uint_as_float(__builtin_amdgcn_readfirstlane(a0.y));
            float w1 = __uint_as_float(__builtin_amdgcn_readfirstlane(a1.y));
            float w2 = __uint_as_float(__builtin_amdgcn_readfirstlane(a2.y));
            float w3 = __uint_as_float(__builtin_amdgcn_readfirstlane(a3.y));
            float v0 = bf2f(support[c0 * NHID + f]);
            float v1 = bf2f(support[c1 * NHID + f]);
            float v2 = bf2f(support[c2 * NHID + f]);
            float v3 = bf2f(support[c3 * NHID + f]);
            acc = fmaf(w0, v0, acc);
            acc = fmaf(w1, v1, acc);
            acc = fmaf(w2, v2, acc);
            acc = fmaf(w3, v3, acc);
        }
        for (; j < je; ++j) {
            int2 a = sorted[j];
            int c = __builtin_amdgcn_readfirstlane(a.x);
            float wgt = __uint_as_float(__builtin_amdgcn_readfirstlane(a.y));
            acc = fmaf(wgt, bf2f(support[c * NHID + f]), acc);
        }
        agg[(size_t)n * NHID + f] = acc;
        s += acc;
        s2 = fmaf(acc, acc, s2);
    }

    __shared__ float red[2][4][64];
    red[0][wv][f] = s;
    red[1][wv][f] = s2;
    __syncthreads();
    if (threadIdx.x < 64) {
        atomicAdd(&sums[f], red[0][0][f] + red[0][1][f] + red[0][2][f] + red[0][3][f]);
    } else if (threadIdx.x < 128) {
        atomicAdd(&sums[64 + f], red[1][0][f] + red[1][1][f] + red[1][2][f] + red[1][3][f]);
    }
}

// ---------------------------------------------------------------------------
// Finalize: scale = gamma*rsqrt(var+eps); shift = beta - mean*scale.
// (reference's +b cancels via BN mean subtraction; b is zeros anyway)
// ---------------------------------------------------------------------------
__global__ __launch_bounds__(64) void finalize_kernel(const float* __restrict__ sums,
                                                      const float* __restrict__ gamma,
                                                      const float* __restrict__ beta,
                                                      float* __restrict__ scaleshift) {
    const int f = threadIdx.x;
    const float inv_n = 1.0f / (float)N_NODES;
    float mean = sums[f] * inv_n;
    float var = sums[64 + f] * inv_n - mean * mean;
    float sc = gamma[f] * rsqrtf(var + 1e-5f);
    scaleshift[f] = sc;
    scaleshift[64 + f] = beta[f] - mean * sc;
}

// ---------------------------------------------------------------------------
// Threefry-2x32, 20 rounds, key=(0,42). Hand-verified vs JAX test vector.
// ---------------------------------------------------------------------------
__device__ __forceinline__ uint32_t rotl32(uint32_t x, int d) {
    return (x << d) | (x >> (32 - d));
}

__device__ __forceinline__ void threefry2x32_0_42(uint32_t x0, uint32_t x1,
                                                  uint32_t& o0, uint32_t& o1) {
    const uint32_t k0 = 0u, k1 = 42u;
    const uint32_t k2 = k0 ^ k1 ^ 0x1BD11BDAu;
    x0 += k0; x1 += k1;
    x0 += x1; x1 = rotl32(x1, 13) ^ x0;
    x0 += x1; x1 = rotl32(x1, 15) ^ x0;
    x0 += x1; x1 = rotl32(x1, 26) ^ x0;
    x0 += x1; x1 = rotl32(x1, 6)  ^ x0;
    x0 += k1; x1 += k2 + 1u;
    x0 += x1; x1 = rotl32(x1, 17) ^ x0;
    x0 += x1; x1 = rotl32(x1, 29) ^ x0;
    x0 += x1; x1 = rotl32(x1, 16) ^ x0;
    x0 += x1; x1 = rotl32(x1, 24) ^ x0;
    x0 += k2; x1 += k0 + 2u;
    x0 += x1; x1 = rotl32(x1, 13) ^ x0;
    x0 += x1; x1 = rotl32(x1, 15) ^ x0;
    x0 += x1; x1 = rotl32(x1, 26) ^ x0;
    x0 += x1; x1 = rotl32(x1, 6)  ^ x0;
    x0 += k0; x1 += k1 + 3u;
    x0 += x1; x1 = rotl32(x1, 17) ^ x0;
    x0 += x1; x1 = rotl32(x1, 29) ^ x0;
    x0 += x1; x1 = rotl32(x1, 16) ^ x0;
    x0 += x1; x1 = rotl32(x1, 24) ^ x0;
    x0 += k1; x1 += k2 + 4u;
    x0 += x1; x1 = rotl32(x1, 13) ^ x0;
    x0 += x1; x1 = rotl32(x1, 15) ^ x0;
    x0 += x1; x1 = rotl32(x1, 26) ^ x0;
    x0 += x1; x1 = rotl32(x1, 6)  ^ x0;
    x0 += k2; x1 += k0 + 5u;
    o0 = x0; o1 = x1;
}

// ---------------------------------------------------------------------------
// Apply: BN affine + ReLU + dropout; f32 out (overwrites dead support).
// ---------------------------------------------------------------------------
__global__ __launch_bounds__(256) void apply_kernel(const float* __restrict__ agg,
                                                    const float* __restrict__ scaleshift,
                                                    float* __restrict__ out) {
    const int i = blockIdx.x * 256 + threadIdx.x;
    if (i >= N_ELEMS) return;
    const int f = i & 63;
    const float sc = scaleshift[f];
    const float sh = scaleshift[64 + f];

    uint32_t o0, o1;
    threefry2x32_0_42(0u, (uint32_t)i, o0, o1);
    uint32_t bits = o0 ^ o1;
    float u = __uint_as_float((bits >> 9) | 0x3F800000u) - 1.0f;

    float v = fmaxf(fmaf(agg[i], sc, sh), 0.0f);
    out[i] = (u < 0.7f) ? v * (1.0f / 0.7f) : 0.0f;
}

// ---------------------------------------------------------------------------
extern "C" void kernel_launch(void* const* d_in, const int* in_sizes, int n_in,
                              void* d_out, int out_size, void* d_ws, size_t ws_size,
                              hipStream_t stream) {
    const float* x     = (const float*)d_in[0];
    const int*   row   = (const int*)d_in[1];
    const int*   col   = (const int*)d_in[2];
    const float* ew    = (const float*)d_in[3];
    const float* W     = (const float*)d_in[4];
    const float* gamma = (const float*)d_in[6];
    const float* beta  = (const float*)d_in[7];
    float* out = (float*)d_out;

    float* sums       = (float*)d_ws;                      // 128
    float* scaleshift = sums + 128;                        // 128
    int*   cnt        = (int*)(scaleshift + 128);          // 100000
    int*   rowptr     = cnt + N_NODES;                     // 100002
    int*   cursor     = rowptr + (N_NODES + 2);            // 100000
    int*   bsum       = cursor + N_NODES;                  // 512
    unsigned short* wt = (unsigned short*)(bsum + 512);    // 16384
    float* agg        = (float*)(wt + 16384);              // 6.4M f32
    int2*  sorted     = (int2*)(agg + (size_t)N_ELEMS);    // 1.6M int2
    unsigned short* support = (unsigned short*)out;        // 6.4M bf16, in d_out

    hipMemsetAsync(d_ws, 0, (size_t)(128 + 128 + N_NODES) * sizeof(float), stream);

    wtprep_kernel<<<64, 256, 0, stream>>>(W, wt);
    gemm_kernel<<<(N_NODES + 63) / 64, 256, 0, stream>>>(x, wt, support);

    const int epb = (N_EDGES + 255) / 256;  // 6250 blocks, 1 thread/edge
    hist_kernel<<<epb, 256, 0, stream>>>(row, cnt);
    scan1_kernel<<<NBLK, 256, 0, stream>>>(cnt, rowptr, bsum);
    scan2_kernel<<<1, 512, 0, stream>>>(bsum);
    scan3_kernel<<<NBLK, 256, 0, stream>>>(rowptr, cursor, bsum);
    bin_kernel<<<epb, 256, 0, stream>>>(row, col, ew, cursor, sorted);

    gather_kernel<<<2048, 256, 0, stream>>>(rowptr, sorted, support, agg, sums);

    finalize_kernel<<<1, 64, 0, stream>>>(sums, gamma, beta, scaleshift);
    apply_kernel<<<(N_ELEMS + 255) / 256, 256, 0, stream>>>(agg, scaleshift, out);
}